// Round 1
// baseline (530.989 us; speedup 1.0000x reference)
//
#include <hip/hip_runtime.h>

#define NN 2304
#define CC 192
#define NBATCH 16

typedef unsigned short u16;
typedef __bf16 bf16x8 __attribute__((ext_vector_type(8)));
typedef float f32x4 __attribute__((ext_vector_type(4)));

__device__ __forceinline__ u16 bf16bits(float f) {
  union { float f; unsigned u; } v;
  v.f = f;
  unsigned r = v.u + 0x7FFFu + ((v.u >> 16) & 1u);
  return (u16)(r >> 16);
}

// XOR-swizzled LDS element index for a [rows][192] bf16 tile (row stride 192).
// 8-element chunks are permuted within 8-chunk groups by row&7: keeps 16B
// alignment for b128 while spreading banks (2-way worst case on frag reads).
__device__ __forceinline__ int swzK(int row, int col) {
  int ch = col >> 3;
  int phys = (ch & ~7) | ((ch ^ row) & 7);
  return row * 192 + (phys << 3) + (col & 7);
}
// Same for [rows][64] tiles (8 chunks per row).
__device__ __forceinline__ int swz64(int row, int col) {
  int ch = (col >> 3) ^ row;
  return (row << 6) | ((ch & 7) << 3) | (col & 7);
}

// ---------------------------------------------------------------------------
// Kernel 1: LayerNorm over C, x[b,c,n] (fp32) -> xn[(b*N+n), c] (bf16)
// ---------------------------------------------------------------------------
__global__ __launch_bounds__(256) void ln_kernel(
    const float* __restrict__ x, const float* __restrict__ lnw,
    const float* __restrict__ lnb, u16* __restrict__ xn) {
  __shared__ float xt[192 * 65];           // [c][n] pad 65 -> conflict-free cols
  __shared__ float psum[4][64], psq[4][64];
  __shared__ float mu_s[64], rs_s[64];
  __shared__ float lw_s[192], lb_s[192];
  int t = threadIdx.x;
  int b = blockIdx.y, n0 = blockIdx.x * 64;
  const float* xb = x + (size_t)b * CC * NN;
  if (t < 192) { lw_s[t] = lnw[t]; lb_s[t] = lnb[t]; }
#pragma unroll
  for (int i = 0; i < 48; ++i) {
    int idx = i * 256 + t;
    int c = idx >> 6, n = idx & 63;
    xt[c * 65 + n] = xb[(size_t)c * NN + n0 + n];   // coalesced 256B runs
  }
  __syncthreads();
  {
    int n = t & 63, part = t >> 6;
    float s = 0.f, s2 = 0.f;
#pragma unroll
    for (int c = part * 48; c < part * 48 + 48; ++c) {
      float v = xt[c * 65 + n];
      s += v; s2 += v * v;
    }
    psum[part][n] = s; psq[part][n] = s2;
  }
  __syncthreads();
  if (t < 64) {
    float s = psum[0][t] + psum[1][t] + psum[2][t] + psum[3][t];
    float s2 = psq[0][t] + psq[1][t] + psq[2][t] + psq[3][t];
    float mu = s * (1.0f / 192.0f);
    float var = s2 * (1.0f / 192.0f) - mu * mu;
    mu_s[t] = mu;
    rs_s[t] = rsqrtf(var + 1e-5f);
  }
  __syncthreads();
#pragma unroll
  for (int i = 0; i < 12; ++i) {
    int u = i * 256 + t;
    int n = u / 48, cq = (u % 48) * 4;
    float mu = mu_s[n], rs = rs_s[n];
    alignas(8) u16 tmp[4];
#pragma unroll
    for (int k2 = 0; k2 < 4; ++k2) {
      float v = (xt[(cq + k2) * 65 + n] - mu) * rs * lw_s[cq + k2] + lb_s[cq + k2];
      tmp[k2] = bf16bits(v);
    }
    *(uint2*)&xn[((size_t)(b * NN + n0 + n)) * CC + cq] = *(uint2*)tmp;
  }
}

// ---------------------------------------------------------------------------
// Kernel 2: QKV projections. y = xn @ W^T (torch Linear). 64x64 tiles, K=192.
// z==2 (V) writes transposed: vt[b][d][n] so attention PV B-frags are rows.
// ---------------------------------------------------------------------------
__global__ __launch_bounds__(256, 3) void qkv_gemm(
    const u16* __restrict__ xn, const float* __restrict__ Wq,
    const float* __restrict__ Wk, const float* __restrict__ Wv,
    u16* __restrict__ qb, u16* __restrict__ kb, u16* __restrict__ vtb) {
  __shared__ u16 xs[12288];   // X tile [64][192] swizzled
  __shared__ u16 wsm[12288];  // W tile [64][192] swizzled (bf16-converted)
  int t = threadIdx.x, w = t >> 6, lane = t & 63, l15 = lane & 15, qd = lane >> 4;
  int m0 = blockIdx.x * 64, n0 = blockIdx.y * 64, z = blockIdx.z;
  const float* W = (z == 0) ? Wq : (z == 1 ? Wk : Wv);
#pragma unroll
  for (int i = 0; i < 6; ++i) {
    int ch = i * 256 + t;
    int row = ch / 24, cin = (ch % 24) * 8;
    *(uint4*)&xs[swzK(row, cin)] = *(const uint4*)&xn[(size_t)(m0 + row) * 192 + cin];
  }
#pragma unroll
  for (int i = 0; i < 6; ++i) {
    int ch = i * 256 + t;
    int row = ch / 24, cin = (ch % 24) * 8;
    const float* src = &W[(size_t)(n0 + row) * 192 + cin];
    alignas(16) u16 tmp[8];
#pragma unroll
    for (int j = 0; j < 8; ++j) tmp[j] = bf16bits(src[j]);
    *(uint4*)&wsm[swzK(row, cin)] = *(uint4*)tmp;
  }
  __syncthreads();
  bf16x8 a[6];
#pragma unroll
  for (int kk = 0; kk < 6; ++kk)
    a[kk] = *(const bf16x8*)&xs[swzK(w * 16 + l15, kk * 32 + qd * 8)];
  const f32x4 fz = {0.f, 0.f, 0.f, 0.f};
  f32x4 acc[4];
#pragma unroll
  for (int ct = 0; ct < 4; ++ct) {
    acc[ct] = fz;
#pragma unroll
    for (int kk = 0; kk < 6; ++kk) {
      bf16x8 bfr = *(const bf16x8*)&wsm[swzK(ct * 16 + l15, kk * 32 + qd * 8)];
      acc[ct] = __builtin_amdgcn_mfma_f32_16x16x32_bf16(a[kk], bfr, acc[ct], 0, 0, 0);
    }
  }
  if (z < 2) {
    u16* outp = (z == 0) ? qb : kb;
#pragma unroll
    for (int ct = 0; ct < 4; ++ct)
#pragma unroll
      for (int r = 0; r < 4; ++r) {
        int m = m0 + w * 16 + qd * 4 + r;
        outp[(size_t)m * 192 + n0 + ct * 16 + l15] = bf16bits(acc[ct][r]);
      }
  } else {
    // transpose 64x64 C-tile via LDS, then coalesced store to vt[b][d][n]
    __syncthreads();
#pragma unroll
    for (int ct = 0; ct < 4; ++ct)
#pragma unroll
      for (int r = 0; r < 4; ++r)
        xs[swz64(ct * 16 + l15, w * 16 + qd * 4 + r)] = bf16bits(acc[ct][r]);
    __syncthreads();
    int b = blockIdx.x / 36, nb = (blockIdx.x % 36) * 64;
#pragma unroll
    for (int i = 0; i < 16; ++i) {
      int idx = i * 256 + t;
      int d = idx >> 6, nn = idx & 63;
      vtb[(size_t)b * 192 * NN + (size_t)(n0 + d) * NN + nb + nn] = xs[swz64(d, nn)];
    }
  }
}

// ---------------------------------------------------------------------------
// Kernel 3: fused flash-style attention.
// Per WG: 64 Q-rows, loop 36 K/V tiles of 64. Dual accumulators:
//   O_soft = exp(S) @ V   (divided by row-sum l at the end, no max-subtract:
//                          exp clamped at 60, |S|~<27 statistically)
//   O_relu = relu(S)^2 @ V
// out = c1*O_soft/l + c2*O_relu + x, c_i = softmax(w1,w2)
// ---------------------------------------------------------------------------
__global__ __launch_bounds__(256, 2) void attn_kernel(
    const u16* __restrict__ qb, const u16* __restrict__ kb,
    const u16* __restrict__ vtb, const float* __restrict__ w1p,
    const float* __restrict__ w2p, const float* __restrict__ x,
    float* __restrict__ out) {
  __shared__ u16 sm[32768];              // exactly 64 KB
  u16* klds = sm;                        // [64][192] K tile (also Q staging)
  u16* vlds = sm + 12288;                // [192][64] V^T tile
  u16* ps = sm + 24576;                  // [64][64] P_soft
  u16* pr = sm + 28672;                  // [64][64] P_relu
  float* olds = (float*)sm;              // epilogue overlay: [192][64] fp32

  int t = threadIdx.x, w = t >> 6, lane = t & 63, l15 = lane & 15, qd = lane >> 4;
  int qt = blockIdx.x, b = blockIdx.y;
  const u16* Qg = qb + ((size_t)b * NN + qt * 64) * 192;
  const u16* Kg = kb + (size_t)b * NN * 192;
  const u16* Vg = vtb + (size_t)b * 192 * NN;

  // stage Q tile into klds, pull A-frags into registers (resident all kernel)
#pragma unroll
  for (int i = 0; i < 6; ++i) {
    int ch = i * 256 + t;
    int row = ch / 24, cin = (ch % 24) * 8;
    *(uint4*)&klds[swzK(row, cin)] = *(const uint4*)&Qg[(size_t)row * 192 + cin];
  }
  __syncthreads();
  bf16x8 qf[6];
#pragma unroll
  for (int kk = 0; kk < 6; ++kk)
    qf[kk] = *(const bf16x8*)&klds[swzK(w * 16 + l15, kk * 32 + qd * 8)];
  __syncthreads();  // Q frags read before first K staging overwrites klds

  const f32x4 fz = {0.f, 0.f, 0.f, 0.f};
  f32x4 os[12], orl[12];
#pragma unroll
  for (int i = 0; i < 12; ++i) { os[i] = fz; orl[i] = fz; }
  float lsum[4] = {0.f, 0.f, 0.f, 0.f};

  for (int kt = 0; kt < 36; ++kt) {
    // stage K tile [64][192] and V^T tile [192][64]
#pragma unroll
    for (int i = 0; i < 6; ++i) {
      int ch = i * 256 + t;
      int row = ch / 24, cin = (ch % 24) * 8;
      *(uint4*)&klds[swzK(row, cin)] =
          *(const uint4*)&Kg[(size_t)(kt * 64 + row) * 192 + cin];
    }
#pragma unroll
    for (int i = 0; i < 6; ++i) {
      int ch = i * 256 + t;
      int row = ch >> 3, cin = (ch & 7) * 8;
      *(uint4*)&vlds[swz64(row, cin)] =
          *(const uint4*)&Vg[(size_t)row * NN + kt * 64 + cin];
    }
    __syncthreads();

    // S = Q @ K^T : wave w -> rows w*16..+16, 4 col-tiles of 16
    f32x4 sacc[4];
#pragma unroll
    for (int ct = 0; ct < 4; ++ct) {
      sacc[ct] = fz;
#pragma unroll
      for (int kk = 0; kk < 6; ++kk) {
        bf16x8 bfr = *(const bf16x8*)&klds[swzK(ct * 16 + l15, kk * 32 + qd * 8)];
        sacc[ct] = __builtin_amdgcn_mfma_f32_16x16x32_bf16(qf[kk], bfr, sacc[ct], 0, 0, 0);
      }
    }

    // exp / relu^2, row-sum for l, write P tiles (C-layout -> LDS -> A-layout)
    float tsum[4] = {0.f, 0.f, 0.f, 0.f};
#pragma unroll
    for (int ct = 0; ct < 4; ++ct)
#pragma unroll
      for (int r = 0; r < 4; ++r) {
        float s = sacc[ct][r];
        float e = __expf(fminf(s, 60.f));
        float rl = (s > 0.f) ? s * s : 0.f;
        tsum[r] += e;
        int row = w * 16 + qd * 4 + r, col = ct * 16 + l15;
        ps[swz64(row, col)] = bf16bits(e);
        pr[swz64(row, col)] = bf16bits(rl);
      }
#pragma unroll
    for (int r = 0; r < 4; ++r) {
      float v = tsum[r];
      v += __shfl_xor(v, 1);
      v += __shfl_xor(v, 2);
      v += __shfl_xor(v, 4);
      v += __shfl_xor(v, 8);
      lsum[r] += v;
    }
    __syncthreads();

    // O += P @ V for both branches; V-frag shared between the two MFMAs
    bf16x8 pfs[2], pfr[2];
#pragma unroll
    for (int kk = 0; kk < 2; ++kk) {
      pfs[kk] = *(const bf16x8*)&ps[swz64(w * 16 + l15, kk * 32 + qd * 8)];
      pfr[kk] = *(const bf16x8*)&pr[swz64(w * 16 + l15, kk * 32 + qd * 8)];
    }
#pragma unroll
    for (int ct = 0; ct < 12; ++ct)
#pragma unroll
      for (int kk = 0; kk < 2; ++kk) {
        bf16x8 vf = *(const bf16x8*)&vlds[swz64(ct * 16 + l15, kk * 32 + qd * 8)];
        os[ct] = __builtin_amdgcn_mfma_f32_16x16x32_bf16(pfs[kk], vf, os[ct], 0, 0, 0);
        orl[ct] = __builtin_amdgcn_mfma_f32_16x16x32_bf16(pfr[kk], vf, orl[ct], 0, 0, 0);
      }
    __syncthreads();  // protect klds/vlds before next staging
  }

  // epilogue: blend, transpose via LDS, residual-add, coalesced store
  float e1 = __expf(w1p[0]), e2 = __expf(w2p[0]);
  float den = e1 + e2;
  float c2f = e2 / den;
  float inv[4];
#pragma unroll
  for (int r = 0; r < 4; ++r) inv[r] = (e1 / den) / lsum[r];
#pragma unroll
  for (int ct = 0; ct < 12; ++ct)
#pragma unroll
    for (int r = 0; r < 4; ++r) {
      int c = ct * 16 + l15, n = w * 16 + qd * 4 + r;
      olds[swz64(c, n)] = os[ct][r] * inv[r] + c2f * orl[ct][r];
    }
  __syncthreads();
  const float* xb = x + (size_t)b * 192 * NN + qt * 64;
  float* ob = out + (size_t)b * 192 * NN + qt * 64;
#pragma unroll
  for (int i = 0; i < 48; ++i) {
    int idx = i * 256 + t;
    int c = idx >> 6, nn = idx & 63;
    ob[(size_t)c * NN + nn] = olds[swz64(c, nn)] + xb[(size_t)c * NN + nn];
  }
}

// ---------------------------------------------------------------------------
extern "C" void kernel_launch(void* const* d_in, const int* in_sizes, int n_in,
                              void* d_out, int out_size, void* d_ws, size_t ws_size,
                              hipStream_t stream) {
  (void)in_sizes; (void)n_in; (void)out_size; (void)ws_size;
  const float* x   = (const float*)d_in[0];
  const float* lnw = (const float*)d_in[1];
  const float* lnb = (const float*)d_in[2];
  const float* Wq  = (const float*)d_in[3];
  const float* Wk  = (const float*)d_in[4];
  const float* Wv  = (const float*)d_in[5];
  const float* w1  = (const float*)d_in[6];
  const float* w2  = (const float*)d_in[7];
  float* out = (float*)d_out;

  // workspace: xn | Q | K | V^T, each B*N*C bf16 = 14.16 MB (total ~56.6 MB)
  u16* xn = (u16*)d_ws;
  size_t per = (size_t)NBATCH * NN * CC;
  u16* qb  = xn + per;
  u16* kb  = qb + per;
  u16* vtb = kb + per;

  ln_kernel<<<dim3(36, 16), 256, 0, stream>>>(x, lnw, lnb, xn);
  qkv_gemm<<<dim3(576, 3, 3), 256, 0, stream>>>(xn, Wq, Wk, Wv, qb, kb, vtb);
  attn_kernel<<<dim3(36, 16), 256, 0, stream>>>(qb, kb, vtb, w1, w2, x, out);
}